// Round 15
// baseline (68.518 us; speedup 1.0000x reference)
//
#include <hip/hip_runtime.h>
#include <hip/hip_bf16.h>
#include <hip/hip_fp8.h>
#include <stdint.h>

// Problem constants (from reference)
#define BATCH 4096
#define D_X   1024
#define D_Y   512

constexpr float SIGMA_INV = 0.1f;    // 1/10.0
constexpr float EPS_THR   = 46.0f;

// ---- fast path: fp8 e4m3 fragment-tiled layout, 128x128 tiles ----
constexpr int BMF   = 128;
constexpr int NTF   = BATCH / BMF;           // 32 tile-rows
constexpr int NBLKF = NTF * (NTF + 1) / 2;   // 528 (528 % 8 == 0)
constexpr int XS8   = D_X / 16;              // 64 16B chunks per fp8 x row
constexpr int YS8   = D_Y / 16;              // 32 chunks per fp8 y row

// ---- fallback tiling (128^2 bf16, round-2 structure) ----
constexpr int BM = 128;
constexpr int NT = BATCH / BM;
constexpr int NBLK = NT * (NT + 1) / 2;

typedef __bf16 bf16x8 __attribute__((ext_vector_type(8)));
typedef float  f32x4  __attribute__((ext_vector_type(4)));
typedef unsigned short u16x8 __attribute__((ext_vector_type(8)));
typedef unsigned long long u64;
typedef u64 u64x2 __attribute__((ext_vector_type(2)));

__device__ __forceinline__ unsigned short f32_to_bf16_bits(float f) {
    unsigned int u = __builtin_bit_cast(unsigned int, f);
    unsigned int r = (u + 0x7FFFu + ((u >> 16) & 1u)) >> 16;  // RNE
    return (unsigned short)r;
}

// R11 k-chunk permutation within each 16-chunk group. perm16(u): stored pos;
// inv16(pos): logical chunk. pos = (u&8) | ((u&3)<<1) | ((u>>2)&1).
__device__ __forceinline__ int inv16(int pos) {
    return (pos & 8) | ((pos >> 1) & 3) | ((pos & 1) << 2);
}

// ===========================================================================
// FAST PATH kernel 1: f32 -> fp8 e4m3 FRAGMENT-TILED layout + quantized norms.
// ft[(R*NCH + sc)*64 + r] (16B units) holds fp8 elems k = lc*16..lc*16+15 of
// row R*64+r, where lc = (sc&~15)|inv16(sc&15). Grid: 64 rowtiles x 6 segs
// (x: 4 segs of 16 chunks; y: 2 segs). LDS transpose; norms of QUANTIZED
// values atomically accumulated (sqx/sqy zeroed by launcher).
// ===========================================================================
__global__ void __launch_bounds__(256)
convert_ft(const float* __restrict__ x, const float* __restrict__ y,
           u16x8* __restrict__ ftx, u16x8* __restrict__ fty,
           float* __restrict__ sqx, float* __restrict__ sqy) {
    __shared__ u16x8 L[64 * 16];          // 16 KB transpose staging
    __shared__ float pn[64];
    const int R   = blockIdx.x / 6;
    const int seg = blockIdx.x % 6;
    const int t   = threadIdx.x;
    const bool isx = (seg < 4);
    const int  cg  = isx ? seg : (seg - 4);     // 16-chunk group index
    const float* src = isx ? x : y;
    const int  ld  = isx ? D_X : D_Y;

    if (t < 64) pn[t] = 0.f;
    __syncthreads();

    // fill: row-major reads, quantize, LDS with XOR swizzle; norm partials
#pragma unroll
    for (int it = 0; it < 4; ++it) {
        int idx = it * 256 + t;           // 0..1023 = 64 rows x 16 chunks
        int r = idx >> 4, jj = idx & 15;
        int lc = cg * 16 + jj;            // logical chunk
        const float4* p = (const float4*)(src + (size_t)(R * 64 + r) * ld + lc * 16);
        float4 f0 = p[0], f1 = p[1], f2 = p[2], f3 = p[3];
        float e[16] = {f0.x, f0.y, f0.z, f0.w, f1.x, f1.y, f1.z, f1.w,
                       f2.x, f2.y, f2.z, f2.w, f3.x, f3.y, f3.z, f3.w};
        u16x8 v;
        float part = 0.f;
#pragma unroll
        for (int i = 0; i < 8; ++i) {
            __hip_fp8_e4m3 q0(e[2 * i]);      // RNE + saturate (OCP)
            __hip_fp8_e4m3 q1(e[2 * i + 1]);
            float b0 = (float)q0, b1 = (float)q1;
            part = fmaf(b0, b0, part);
            part = fmaf(b1, b1, part);
            v[i] = (unsigned short)(q0.__x | ((unsigned short)q1.__x << 8));
        }
        L[r * 16 + (jj ^ (r & 15))] = v;
        atomicAdd(&pn[r], part);
    }
    __syncthreads();
    // drain: transposed read, coalesced fragment-tiled write (perm16 applied)
#pragma unroll
    for (int it = 0; it < 4; ++it) {
        int idx = it * 256 + t;
        int scl = idx >> 6, r = idx & 63;     // scl 0..15 across iters
        int sc  = cg * 16 + (it * 4 + (t >> 6));
        (void)scl;
        int lc  = (sc & ~15) | inv16(sc & 15);
        int jj  = lc - cg * 16;
        u16x8 v = L[r * 16 + (jj ^ (r & 15))];
        if (isx) ftx[((size_t)R * XS8 + sc) * 64 + r] = v;
        else     fty[((size_t)R * YS8 + sc) * 64 + r] = v;
    }
    __syncthreads();
    if (t < 64) atomicAdd((isx ? sqx : sqy) + R * 64 + t, pn[t]);
}

// ===========================================================================
// FAST PATH kernel 2: 128^2 fp8 tiles, A-operands DIRECT FROM GLOBAL
// (fragment-tiled, L1/L2-served, double-buffered regs, 1-step prefetch),
// B-half staged to LDS (2 x 16 KB dbuf, source-swizzled, conflict-free b128
// reads). LDS pipe per block-step: 48 KB (was 96). Depth-2 counted vmcnt.
// global_load_lds offset arg stays 0 (R12 lesson); offsets via pointer math.
// ===========================================================================

__device__ __forceinline__ u64x2 ldsfrag2(const u16x8* T, int row, int c) {
    int slot = c ^ (row & 7);
    return __builtin_bit_cast(u64x2, T[row * 8 + slot]);
}

// Stage B tile: 128 rows x 8 slots = 16 KB; 4 global_load_lds per thread.
#define ISSUE(DST, BASE, OFF)                                              \
    {                                                                      \
        _Pragma("unroll")                                                  \
        for (int it = 0; it < 4; ++it)                                     \
            __builtin_amdgcn_global_load_lds(                              \
                (const uint32_t __attribute__((address_space(1)))*)(BASE[it] + (OFF)), \
                (uint32_t __attribute__((address_space(3)))*)((DST) + it * 256 + wid * 64), \
                16, 0, 0);                                                 \
    }

#define AREAD(DST, APTR, AOFF)                                             \
    _Pragma("unroll")                                                      \
    for (int t2 = 0; t2 < 2; ++t2)                                         \
        _Pragma("unroll")                                                  \
        for (int m = 0; m < 4; ++m)                                        \
            DST[t2][m] = *(const u64x2*)((APTR) + (AOFF) + t2 * 4096 + m * 256);

#define BREAD(FB, BUF)                                                     \
    _Pragma("unroll")                                                      \
    for (int t2 = 0; t2 < 2; ++t2)                                         \
        _Pragma("unroll")                                                  \
        for (int n = 0; n < 4; ++n)                                        \
            FB[t2][n] = ldsfrag2(BUF, wc * 64 + n * 16 + lrow, t2 * 4 + kgrp);

#define MFMA8(FA, FB, ACC)                                                 \
        __builtin_amdgcn_s_setprio(1);                                     \
        _Pragma("unroll")                                                  \
        for (int t2 = 0; t2 < 2; ++t2)                                     \
            _Pragma("unroll")                                              \
            for (int h = 0; h < 2; ++h)                                    \
                _Pragma("unroll")                                          \
                for (int m = 0; m < 4; ++m)                                \
                    _Pragma("unroll")                                      \
                    for (int n = 0; n < 4; ++n)                            \
                        ACC[m][n] =                                        \
                            __builtin_amdgcn_mfma_f32_16x16x32_fp8_fp8(    \
                                (long)FA[t2][m][h], (long)FB[t2][n][h],    \
                                ACC[m][n], 0, 0, 0);                       \
        __builtin_amdgcn_s_setprio(0);

// Full step: wait staged B, read B frags + NEXT step's A frags, stage B for
// step+2, MFMA with CURRENT A frags.
#define GSTEP(BUF, ACC, W, BOFF, FCUR, FNXT, APTR, AOFF)                   \
    {                                                                      \
        asm volatile("s_waitcnt vmcnt(" #W ")" ::: "memory");              \
        __builtin_amdgcn_s_barrier();                                      \
        u64x2 fb[2][4];                                                    \
        BREAD(fb, BUF)                                                     \
        AREAD(FNXT, APTR, AOFF)                                            \
        asm volatile("s_waitcnt lgkmcnt(0)" ::: "memory");                 \
        __builtin_amdgcn_s_barrier();                                      \
        ISSUE(BUF, g, BOFF)                                                \
        MFMA8(FCUR, fb, ACC)                                               \
    }
#define GSTEP_NIR(BUF, ACC, W, FCUR, FNXT, APTR, AOFF)                     \
    {                                                                      \
        asm volatile("s_waitcnt vmcnt(" #W ")" ::: "memory");              \
        __builtin_amdgcn_s_barrier();                                      \
        u64x2 fb[2][4];                                                    \
        BREAD(fb, BUF)                                                     \
        AREAD(FNXT, APTR, AOFF)                                            \
        MFMA8(FCUR, fb, ACC)                                               \
    }
#define GSTEP_NI(BUF, ACC, W, FCUR)                                        \
    {                                                                      \
        asm volatile("s_waitcnt vmcnt(" #W ")" ::: "memory");              \
        __builtin_amdgcn_s_barrier();                                      \
        u64x2 fb[2][4];                                                    \
        BREAD(fb, BUF)                                                     \
        MFMA8(FCUR, fb, ACC)                                               \
    }

__global__ void __launch_bounds__(256, 2)
gram_fp8(const u16x8* __restrict__ ftx, const u16x8* __restrict__ fty,
         const float* __restrict__ sqx, const float* __restrict__ sqy,
         float* __restrict__ out) {
    __shared__ u16x8 B0[1024], B1[1024];   // 2 x 16 KB B tiles
    __shared__ float snxA[BMF], snxB[BMF], snyA[BMF], snyB[BMF];
    __shared__ float wsum[4];

    const int tid  = threadIdx.x;
    const int lane = tid & 63;
    const int wid  = tid >> 6;
    const int wr   = wid >> 1;
    const int wc   = wid & 1;
    const int lrow = lane & 15;
    const int kgrp = lane >> 4;

    // XCD swizzle (bijective: NBLKF % 8 == 0).
    int sb = (blockIdx.x & 7) * (NBLKF / 8) + (blockIdx.x >> 3);

    // triangular tile mapping
    int t0 = sb, bi = 0;
    while (t0 >= NTF - bi) { t0 -= NTF - bi; ++bi; }
    const int bj = bi + t0;
    const int iA = bi * BMF;
    const int iB = bj * BMF;
    const bool diag = (bi == bj);

    if (tid < BMF) {
        snxA[tid] = sqx[iA + tid];
        snyA[tid] = sqy[iA + tid];
    } else {
        int u = tid - BMF;
        snxB[u] = sqx[iB + u];
        snyB[u] = sqy[iB + u];
    }

    // B-staging per-lane base pointers (x first; switched to y before s6's
    // issue). Lane ul = it*256 + wid*64 + lane -> (B-row rr, stored slot st);
    // source-swizzle folded: logical slot lg = st ^ (rr&7). Step off = s*8192.
    const char* g[4];
#pragma unroll
    for (int it = 0; it < 4; ++it) {
        int ul = it * 256 + wid * 64 + lane;
        int rr = ul >> 3, st = ul & 7;
        int lg = st ^ (rr & 7);
        g[it] = (const char*)ftx +
                (((size_t)(iB / 64 + (rr >> 6)) * XS8 + lg) * 64 + (rr & 63)) * 16;
    }
    // A fragment base pointers (kgrp, lrow folded); per (t2,m): +t2*4096+m*256.
    const char* Ax = (const char*)ftx +
        (((size_t)(iA / 64 + wr) * XS8 + kgrp) * 64 + lrow) * 16;
    const char* Ay = (const char*)fty +
        (((size_t)(iA / 64 + wr) * YS8 + kgrp) * 64 + lrow) * 16;

    f32x4 accX[4][4] = {};
    f32x4 accY[4][4] = {};
    u64x2 fa0[2][4], fa1[2][4];

    // prologue: stage B s0,s1; read A frags for s0
    ISSUE(B0, g, 0)
    ISSUE(B1, g, 8192)
    AREAD(fa0, Ax, 0)

    // X: steps 0..7 (BK=128 each)
    GSTEP(B0, accX, 4, 2 * 8192, fa0, fa1, Ax, 1 * 8192)   // s0, stage s2
    GSTEP(B1, accX, 4, 3 * 8192, fa1, fa0, Ax, 2 * 8192)   // s1
    GSTEP(B0, accX, 4, 4 * 8192, fa0, fa1, Ax, 3 * 8192)   // s2
    GSTEP(B1, accX, 4, 5 * 8192, fa1, fa0, Ax, 4 * 8192)   // s3
    GSTEP(B0, accX, 4, 6 * 8192, fa0, fa1, Ax, 5 * 8192)   // s4
    GSTEP(B1, accX, 4, 7 * 8192, fa1, fa0, Ax, 6 * 8192)   // s5
    // switch B-staging bases to y (per-thread, no sync needed)
#pragma unroll
    for (int it = 0; it < 4; ++it) {
        int ul = it * 256 + wid * 64 + lane;
        int rr = ul >> 3, st = ul & 7;
        int lg = st ^ (rr & 7);
        g[it] = (const char*)fty +
                (((size_t)(iB / 64 + (rr >> 6)) * YS8 + lg) * 64 + (rr & 63)) * 16;
    }
    GSTEP(B0, accX, 4, 0,        fa0, fa1, Ax, 7 * 8192)   // s6, stage s8 (y0)
    GSTEP(B1, accX, 4, 1 * 8192, fa1, fa0, Ay, 0)          // s7, stage s9
    // Y: steps 8..11
    GSTEP(B0, accY, 4, 2 * 8192, fa0, fa1, Ay, 1 * 8192)   // s8, stage s10
    GSTEP(B1, accY, 4, 3 * 8192, fa1, fa0, Ay, 2 * 8192)   // s9, stage s11
    GSTEP_NIR(B0, accY, 4, fa0, fa1, Ay, 3 * 8192)         // s10
    GSTEP_NI(B1, accY, 0, fa1)                             // s11 (full drain)

    // Epilogue: C/D layout col=lane&15, row=(lane>>4)*4+reg (m89, dtype-indep)
    float local = 0.f;
#pragma unroll
    for (int m = 0; m < 4; ++m) {
#pragma unroll
        for (int n = 0; n < 4; ++n) {
            int col   = wc * 64 + n * 16 + lrow;
            float sxj = snxB[col];
            float syj = snyB[col];
#pragma unroll
            for (int r = 0; r < 4; ++r) {
                int rowi  = wr * 64 + m * 16 + kgrp * 4 + r;
                float d2x = snxA[rowi] + sxj - 2.f * accX[m][n][r];
                float dxv = sqrtf(fmaxf(d2x, 1e-12f));
                float d2y = snyA[rowi] + syj - 2.f * accY[m][n][r];
                float dyv = sqrtf(fmaxf(d2y, 1e-12f));
                int gi = iA + rowi, gj = iB + col;
                bool keep = (gi != gj) && (dxv <= EPS_THR);
                float contrib = __expf(-dxv * SIGMA_INV) * dyv;
                local += keep ? contrib : 0.f;
            }
        }
    }
    if (!diag) local *= 2.f;

#pragma unroll
    for (int off = 32; off > 0; off >>= 1)
        local += __shfl_down(local, off, 64);
    if (lane == 0) wsum[wid] = local;
    __syncthreads();
    if (tid == 0)
        atomicAdd(out, wsum[0] + wsum[1] + wsum[2] + wsum[3]);
}

// ===========================================================================
// FALLBACK PATH (bf16, round-2 structure) — used only if ws too small.
// ===========================================================================
__global__ void norms_kernel_fb(const float* __restrict__ x,
                                const float* __restrict__ y,
                                float* __restrict__ sqx,
                                float* __restrict__ sqy) {
    int row = blockIdx.x;
    int t   = threadIdx.x;
    const float4* xr = (const float4*)(x + (size_t)row * D_X);
    float sx = 0.f;
#pragma unroll
    for (int i = 0; i < D_X / 4 / 64; ++i) {
        float4 v = xr[t + i * 64];
        sx += v.x * v.x + v.y * v.y + v.z * v.z + v.w * v.w;
    }
    const float4* yr = (const float4*)(y + (size_t)row * D_Y);
    float sy = 0.f;
#pragma unroll
    for (int i = 0; i < D_Y / 4 / 64; ++i) {
        float4 v = yr[t + i * 64];
        sy += v.x * v.x + v.y * v.y + v.z * v.z + v.w * v.w;
    }
#pragma unroll
    for (int off = 32; off > 0; off >>= 1) {
        sx += __shfl_down(sx, off, 64);
        sy += __shfl_down(sy, off, 64);
    }
    if (t == 0) { sqx[row] = sx; sqy[row] = sy; }
}

__device__ __forceinline__ void stage_tile_fb(const float* __restrict__ src, int ld,
                                              int base_row, int k0,
                                              u16x8* __restrict__ dst, int tid) {
#pragma unroll
    for (int it = 0; it < 2; ++it) {
        int u   = tid + it * 256;
        int row = u >> 2;
        int q   = u & 3;
        const float4* p = (const float4*)(src + (size_t)(base_row + row) * ld + k0 + q * 16);
        float4 f0 = p[0], f1 = p[1], f2 = p[2], f3 = p[3];
        u16x8 lo, hi;
        lo[0] = f32_to_bf16_bits(f0.x); lo[1] = f32_to_bf16_bits(f0.y);
        lo[2] = f32_to_bf16_bits(f0.z); lo[3] = f32_to_bf16_bits(f0.w);
        lo[4] = f32_to_bf16_bits(f1.x); lo[5] = f32_to_bf16_bits(f1.y);
        lo[6] = f32_to_bf16_bits(f1.z); lo[7] = f32_to_bf16_bits(f1.w);
        hi[0] = f32_to_bf16_bits(f2.x); hi[1] = f32_to_bf16_bits(f2.y);
        hi[2] = f32_to_bf16_bits(f2.z); hi[3] = f32_to_bf16_bits(f2.w);
        hi[4] = f32_to_bf16_bits(f3.x); hi[5] = f32_to_bf16_bits(f3.y);
        hi[6] = f32_to_bf16_bits(f3.z); hi[7] = f32_to_bf16_bits(f3.w);
        int swz = row & 7;
        dst[row * 8 + ((2 * q) ^ swz)]     = lo;
        dst[row * 8 + ((2 * q + 1) ^ swz)] = hi;
    }
}

__device__ __forceinline__ void mfma16_fb(const bf16x8 a[4], const bf16x8 b[4],
                                          f32x4 acc[4][4]) {
#pragma unroll
    for (int m = 0; m < 4; ++m)
#pragma unroll
        for (int n = 0; n < 4; ++n)
            acc[m][n] = __builtin_amdgcn_mfma_f32_16x16x32_bf16(
                a[m], b[n], acc[m][n], 0, 0, 0);
}

__device__ __forceinline__ void load_frags_fb(const u16x8* As_, const u16x8* Bs_,
                                              int wr, int wc, int lrow, int kgrp,
                                              bf16x8 a[2][4], bf16x8 b[2][4]) {
#pragma unroll
    for (int ks = 0; ks < 2; ++ks) {
#pragma unroll
        for (int m = 0; m < 4; ++m) {
            int row  = wr * 64 + m * 16 + lrow;
            int slot = (ks * 4 + kgrp) ^ (row & 7);
            a[ks][m] = __builtin_bit_cast(bf16x8, As_[row * 8 + slot]);
        }
#pragma unroll
        for (int n = 0; n < 4; ++n) {
            int row  = wc * 64 + n * 16 + lrow;
            int slot = (ks * 4 + kgrp) ^ (row & 7);
            b[ks][n] = __builtin_bit_cast(bf16x8, Bs_[row * 8 + slot]);
        }
    }
}

__global__ void __launch_bounds__(256, 2)
graph_loss_fb(const float* __restrict__ x, const float* __restrict__ y,
              const float* __restrict__ sqx, const float* __restrict__ sqy,
              float* __restrict__ out) {
    __shared__ u16x8 As[BM * 8];
    __shared__ u16x8 Bs[BM * 8];
    __shared__ float snxA[BM], snxB[BM], snyA[BM], snyB[BM];
    __shared__ float wsum[4];

    const int tid  = threadIdx.x;
    const int lane = tid & 63;
    const int wid  = tid >> 6;
    const int wr   = wid >> 1;
    const int wc   = wid & 1;
    const int lrow = lane & 15;
    const int kgrp = lane >> 4;

    int t = blockIdx.x, bi = 0;
    while (t >= NT - bi) { t -= NT - bi; ++bi; }
    const int bj = bi + t;
    const int iA = bi * BM;
    const int iB = bj * BM;

    if (tid < BM) {
        snxA[tid] = sqx[iA + tid];
        snyA[tid] = sqy[iA + tid];
        snxB[tid] = sqx[iB + tid];
        snyB[tid] = sqy[iB + tid];
    }

    f32x4 accX[4][4] = {};
    f32x4 accY[4][4] = {};
    bf16x8 a[2][4], b[2][4];

    for (int kt = 0; kt < D_X / 64; ++kt) {
        __syncthreads();
        stage_tile_fb(x, D_X, iA, kt * 64, As, tid);
        stage_tile_fb(x, D_X, iB, kt * 64, Bs, tid);
        __syncthreads();
        load_frags_fb(As, Bs, wr, wc, lrow, kgrp, a, b);
#pragma unroll
        for (int ks = 0; ks < 2; ++ks) mfma16_fb(a[ks], b[ks], accX);
    }
    for (int kt = 0; kt < D_Y / 64; ++kt) {
        __syncthreads();
        stage_tile_fb(y, D_Y, iA, kt * 64, As, tid);
        stage_tile_fb(y, D_Y, iB, kt * 64, Bs, tid);
        __syncthreads();
        load_frags_fb(As, Bs, wr, wc, lrow, kgrp, a, b);
#pragma unroll
        for (int ks = 0; ks < 2; ++ks) mfma16_fb(a[ks], b[ks], accY);
    }

    float local = 0.f;
#pragma unroll
    for (int m = 0; m < 4; ++m) {
#pragma unroll
        for (int n = 0; n < 4; ++n) {
            int col   = wc * 64 + n * 16 + lrow;
            float sxj = snxB[col];
            float syj = snyB[col];
#pragma unroll
            for (int r = 0; r < 4; ++r) {
                int rowi  = wr * 64 + m * 16 + kgrp * 4 + r;
                float d2x = snxA[rowi] + sxj - 2.f * accX[m][n][r];
                float dxv = sqrtf(fmaxf(d2x, 1e-12f));
                float d2y = snyA[rowi] + syj - 2.f * accY[m][n][r];
                float dyv = sqrtf(fmaxf(d2y, 1e-12f));
                int gi = iA + rowi, gj = iB + col;
                bool keep = (gi != gj) && (dxv <= EPS_THR);
                float contrib = __expf(-dxv * SIGMA_INV) * dyv;
                local += keep ? contrib : 0.f;
            }
        }
    }
    if (bi != bj) local *= 2.f;

#pragma unroll
    for (int off = 32; off > 0; off >>= 1)
        local += __shfl_down(local, off, 64);
    if (lane == 0) wsum[wid] = local;
    __syncthreads();
    if (tid == 0)
        atomicAdd(out, wsum[0] + wsum[1] + wsum[2] + wsum[3]);
}

// ===========================================================================
extern "C" void kernel_launch(void* const* d_in, const int* in_sizes, int n_in,
                              void* d_out, int out_size, void* d_ws, size_t ws_size,
                              hipStream_t stream) {
    const float* x = (const float*)d_in[0];
    const float* y = (const float*)d_in[1];
    float* out = (float*)d_out;

    hipMemsetAsync(d_out, 0, sizeof(float) * (size_t)out_size, stream);

    const size_t ftx_bytes = (size_t)BATCH * D_X;       // 4 MB fp8
    const size_t fty_bytes = (size_t)BATCH * D_Y;       // 2 MB fp8
    const size_t sq_bytes  = 2 * (size_t)BATCH * sizeof(float);
    const size_t need = ftx_bytes + fty_bytes + sq_bytes;

    if (ws_size >= need) {
        u16x8* ftx = (u16x8*)d_ws;
        u16x8* fty = (u16x8*)((char*)d_ws + ftx_bytes);
        float* sqx = (float*)((char*)d_ws + ftx_bytes + fty_bytes);
        float* sqy = sqx + BATCH;
        // norms are atomically accumulated -> zero first
        hipMemsetAsync(sqx, 0, sq_bytes, stream);
        convert_ft<<<64 * 6, 256, 0, stream>>>(x, y, ftx, fty, sqx, sqy);
        gram_fp8<<<NBLKF, 256, 0, stream>>>(ftx, fty, sqx, sqy, out);
    } else {
        float* sqx = (float*)d_ws;
        float* sqy = sqx + BATCH;
        norms_kernel_fb<<<BATCH, 64, 0, stream>>>(x, y, sqx, sqy);
        graph_loss_fb<<<NBLK, 256, 0, stream>>>(x, y, sqx, sqy, out);
    }
}

// Round 16
// 59.310 us; speedup vs baseline: 1.1552x; 1.1552x over previous
//
#include <hip/hip_runtime.h>
#include <hip/hip_bf16.h>
#include <hip/hip_fp8.h>
#include <stdint.h>

// Problem constants (from reference)
#define BATCH 4096
#define D_X   1024
#define D_Y   512

constexpr float SIGMA_INV = 0.1f;    // 1/10.0
constexpr float EPS_THR   = 46.0f;

// ---- fast path: fp8 e4m3, 128x128 triangular tiles, BK=64, 3 LDS bufs ----
constexpr int BMF   = 128;
constexpr int NTF   = BATCH / BMF;           // 32 tile-rows
constexpr int NBLKF = NTF * (NTF + 1) / 2;   // 528 (528 % 8 == 0)
constexpr int XS8   = D_X / 16;              // 64 16B chunks per fp8 x row
constexpr int YS8   = D_Y / 16;              // 32 chunks per fp8 y row

// ---- fallback tiling (128^2 bf16, round-2 structure) ----
constexpr int BM = 128;
constexpr int NT = BATCH / BM;
constexpr int NBLK = NT * (NT + 1) / 2;

typedef __bf16 bf16x8 __attribute__((ext_vector_type(8)));
typedef float  f32x4  __attribute__((ext_vector_type(4)));
typedef unsigned short u16x8 __attribute__((ext_vector_type(8)));
typedef unsigned long long u64;
typedef u64 u64x2 __attribute__((ext_vector_type(2)));

__device__ __forceinline__ unsigned short f32_to_bf16_bits(float f) {
    unsigned int u = __builtin_bit_cast(unsigned int, f);
    unsigned int r = (u + 0x7FFFu + ((u >> 16) & 1u)) >> 16;  // RNE
    return (unsigned short)r;
}

// R11 k-unit permutation: logical u8 (ks=u8>>2, kg=u8&3) -> stored pos so a
// BK=64 step occupies 4 consecutive 16B chunks (chunk index s*4+kg), each
// chunk = the step's two k=32 sub-blocks for one kgrp, read by ONE
// conflict-free ds_read_b128.
__device__ __forceinline__ int perm16(int u8) {
    int ks = u8 >> 2, kg = u8 & 3;
    return (ks >> 1) * 8 + kg * 2 + (ks & 1);
}

// ===========================================================================
// FAST PATH kernel 1: f32 -> fp8 e4m3 (permuted k-order) + norms of the
// QUANTIZED values (so d2 = ||q_i - q_j||^2 is exact for quantized vectors).
// ===========================================================================
__global__ void __launch_bounds__(192)
convert_fp8(const float* __restrict__ x, const float* __restrict__ y,
            u64* __restrict__ xq, u64* __restrict__ yq,
            float* __restrict__ sqx, float* __restrict__ sqy) {
    __shared__ float part[2];
    const int row = blockIdx.x;
    const int t   = threadIdx.x;
    const int lane = t & 63;
    const int wid  = t >> 6;

    float nrm = 0.f;
    if (t < 128) {
        const float4* p = (const float4*)(x + (size_t)row * D_X + t * 8);
        float4 f0 = p[0], f1 = p[1];
        float e[8] = {f0.x, f0.y, f0.z, f0.w, f1.x, f1.y, f1.z, f1.w};
        u64 w = 0;
#pragma unroll
        for (int i = 0; i < 8; ++i) {
            __hip_fp8_e4m3 q(e[i]);                  // RNE + saturate (OCP)
            float b = (float)q;
            nrm = fmaf(b, b, nrm);
            w |= (u64)q.__x << (8 * i);
        }
        xq[(size_t)row * 128 + (t & ~15) + perm16(t & 15)] = w;
    } else {
        int o = t - 128;                             // 0..63
        const float4* p = (const float4*)(y + (size_t)row * D_Y + o * 8);
        float4 f0 = p[0], f1 = p[1];
        float e[8] = {f0.x, f0.y, f0.z, f0.w, f1.x, f1.y, f1.z, f1.w};
        u64 w = 0;
#pragma unroll
        for (int i = 0; i < 8; ++i) {
            __hip_fp8_e4m3 q(e[i]);
            float b = (float)q;
            nrm = fmaf(b, b, nrm);
            w |= (u64)q.__x << (8 * i);
        }
        yq[(size_t)row * 64 + (o & ~15) + perm16(o & 15)] = w;
    }
#pragma unroll
    for (int off = 32; off > 0; off >>= 1)
        nrm += __shfl_down(nrm, off, 64);
    if (lane == 0) {
        if (wid < 2) part[wid] = nrm;
        else         sqy[row] = nrm;
    }
    __syncthreads();
    if (t == 0) sqx[row] = part[0] + part[1];
}

// ===========================================================================
// FAST PATH kernel 2: 128^2 fp8 tiles, BK=64, 3 cyclic 16KB buffers, ONE
// barrier per step. Step s reads B[s%3], issues staging for step s+2 into
// B[(s+2)%3] (= the buffer all waves finished reading at step s-1, whose
// lgkm waits preceded this step's barrier -> safe without a mid barrier).
// Counted vmcnt(4) (batch s+1 stays in flight). Per wave: 64x64 output,
// 32 MFMA/step, 8 conflict-free ds_read_b128/step.
// global_load_lds offset arg stays 0 (R12: imm applies to BOTH addresses).
// ===========================================================================

__device__ __forceinline__ u64x2 ldsfrag4(const u16x8* T, int row, int kg) {
    return __builtin_bit_cast(u64x2, T[row * 4 + (kg ^ (row & 3))]);
}

// Stage one BK=64 step: 256 rows x 4 chunks = 16 KB; 4 gload_lds per thread.
#define ISSUE(DST, BASE, OFF)                                              \
    {                                                                      \
        _Pragma("unroll")                                                  \
        for (int it = 0; it < 4; ++it)                                     \
            __builtin_amdgcn_global_load_lds(                              \
                (const uint32_t __attribute__((address_space(1)))*)(BASE[it] + (OFF)), \
                (uint32_t __attribute__((address_space(3)))*)((DST) + it * 256 + wid * 64), \
                16, 0, 0);                                                 \
    }

#define MFMA_BLK(FA, FB, ACC)                                              \
        __builtin_amdgcn_s_setprio(1);                                     \
        _Pragma("unroll")                                                  \
        for (int h = 0; h < 2; ++h)                                        \
            _Pragma("unroll")                                              \
            for (int m = 0; m < 4; ++m)                                    \
                _Pragma("unroll")                                          \
                for (int n = 0; n < 4; ++n)                                \
                    ACC[m][n] = __builtin_amdgcn_mfma_f32_16x16x32_fp8_fp8(\
                        (long)FA[m][h], (long)FB[n][h], ACC[m][n], 0,0,0); \
        __builtin_amdgcn_s_setprio(0);

// One step: vmcnt(4) + single barrier; read frags; issue s+2; MFMA.
#define GS(RB, WB, GSRC, GOFF, ACC)                                        \
    {                                                                      \
        asm volatile("s_waitcnt vmcnt(4)" ::: "memory");                   \
        __builtin_amdgcn_s_barrier();                                      \
        u64x2 fa[4], fb[4];                                                \
        _Pragma("unroll")                                                  \
        for (int m = 0; m < 4; ++m)                                        \
            fa[m] = ldsfrag4(RB, wr * 64 + m * 16 + lrow, kgrp);           \
        _Pragma("unroll")                                                  \
        for (int n = 0; n < 4; ++n)                                        \
            fb[n] = ldsfrag4(RB, 128 + wc * 64 + n * 16 + lrow, kgrp);     \
        ISSUE(WB, GSRC, GOFF)                                              \
        MFMA_BLK(fa, fb, ACC)                                              \
    }
#define GS_NI4(RB, ACC)                                                    \
    {                                                                      \
        asm volatile("s_waitcnt vmcnt(4)" ::: "memory");                   \
        __builtin_amdgcn_s_barrier();                                      \
        u64x2 fa[4], fb[4];                                                \
        _Pragma("unroll")                                                  \
        for (int m = 0; m < 4; ++m)                                        \
            fa[m] = ldsfrag4(RB, wr * 64 + m * 16 + lrow, kgrp);           \
        _Pragma("unroll")                                                  \
        for (int n = 0; n < 4; ++n)                                        \
            fb[n] = ldsfrag4(RB, 128 + wc * 64 + n * 16 + lrow, kgrp);     \
        MFMA_BLK(fa, fb, ACC)                                              \
    }
#define GS_NI0(RB, ACC)                                                    \
    {                                                                      \
        asm volatile("s_waitcnt vmcnt(0)" ::: "memory");                   \
        __builtin_amdgcn_s_barrier();                                      \
        u64x2 fa[4], fb[4];                                                \
        _Pragma("unroll")                                                  \
        for (int m = 0; m < 4; ++m)                                        \
            fa[m] = ldsfrag4(RB, wr * 64 + m * 16 + lrow, kgrp);           \
        _Pragma("unroll")                                                  \
        for (int n = 0; n < 4; ++n)                                        \
            fb[n] = ldsfrag4(RB, 128 + wc * 64 + n * 16 + lrow, kgrp);     \
        MFMA_BLK(fa, fb, ACC)                                              \
    }

__global__ void __launch_bounds__(256, 2)
gram_fp8(const u16x8* __restrict__ xq, const u16x8* __restrict__ yq,
         const float* __restrict__ sqx, const float* __restrict__ sqy,
         float* __restrict__ out) {
    __shared__ u16x8 B0[1024], B1[1024], B2[1024];   // 3 x 16 KB
    __shared__ float snxA[BMF], snxB[BMF], snyA[BMF], snyB[BMF];
    __shared__ float wsum[4];

    const int tid  = threadIdx.x;
    const int lane = tid & 63;
    const int wid  = tid >> 6;
    const int wr   = wid >> 1;
    const int wc   = wid & 1;
    const int lrow = lane & 15;
    const int kgrp = lane >> 4;

    // XCD swizzle (bijective: NBLKF % 8 == 0).
    int sb = (blockIdx.x & 7) * (NBLKF / 8) + (blockIdx.x >> 3);

    // triangular tile mapping
    int t0 = sb, bi = 0;
    while (t0 >= NTF - bi) { t0 -= NTF - bi; ++bi; }
    const int bj = bi + t0;
    const int iA = bi * BMF;
    const int iB = bj * BMF;
    const bool diag = (bi == bj);

    if (tid < BMF) {
        snxA[tid] = sqx[iA + tid];
        snyA[tid] = sqy[iA + tid];
    } else {
        int u = tid - BMF;
        snxB[u] = sqx[iB + u];
        snyB[u] = sqy[iB + u];
    }

    // Per-lane staging bases. Lane ul = it*256 + wid*64 + lane maps to
    // (row 0..255, stored slot st 0..3); source-swizzle folded:
    // logical chunk-in-step lg = st ^ (row&3). Step s stages bytes s*64
    // past the base (chunk s*4+lg of the row).
    const char* gx[4];
    const char* gy[4];
#pragma unroll
    for (int it = 0; it < 4; ++it) {
        int ul   = it * 256 + wid * 64 + lane;
        int row  = ul >> 2;
        int st   = ul & 3;
        int lg   = st ^ (row & 3);
        int grow = (row < 128 ? iA + row : iB + row - 128);
        gx[it] = (const char*)xq + (size_t)grow * (XS8 * 16) + lg * 16;
        gy[it] = (const char*)yq + (size_t)grow * (YS8 * 16) + lg * 16;
    }

    f32x4 accX[4][4] = {};
    f32x4 accY[4][4] = {};

    // prologue: pre-issue steps 0,1 (8 loads in flight; no drain)
    ISSUE(B0, gx, 0)
    ISSUE(B1, gx, 64)

    // 24 steps: s reads B[s%3], issues s+2 into B[(s+2)%3].
    GS(B0, B2, gx, 128, accX)   // s0
    GS(B1, B0, gx, 192, accX)   // s1
    GS(B2, B1, gx, 256, accX)   // s2
    GS(B0, B2, gx, 320, accX)   // s3
    GS(B1, B0, gx, 384, accX)   // s4
    GS(B2, B1, gx, 448, accX)   // s5
    GS(B0, B2, gx, 512, accX)   // s6
    GS(B1, B0, gx, 576, accX)   // s7
    GS(B2, B1, gx, 640, accX)   // s8
    GS(B0, B2, gx, 704, accX)   // s9
    GS(B1, B0, gx, 768, accX)   // s10
    GS(B2, B1, gx, 832, accX)   // s11
    GS(B0, B2, gx, 896, accX)   // s12
    GS(B1, B0, gx, 960, accX)   // s13
    GS(B2, B1, gy, 0,   accX)   // s14 (issues first Y step)
    GS(B0, B2, gy, 64,  accX)   // s15
    GS(B1, B0, gy, 128, accY)   // s16
    GS(B2, B1, gy, 192, accY)   // s17
    GS(B0, B2, gy, 256, accY)   // s18
    GS(B1, B0, gy, 320, accY)   // s19
    GS(B2, B1, gy, 384, accY)   // s20
    GS(B0, B2, gy, 448, accY)   // s21
    GS_NI4(B1, accY)            // s22 (batch 23 in flight)
    GS_NI0(B2, accY)            // s23 (full drain)

    // Epilogue: C/D layout col=lane&15, row=(lane>>4)*4+reg (m89, dtype-indep)
    float local = 0.f;
#pragma unroll
    for (int m = 0; m < 4; ++m) {
#pragma unroll
        for (int n = 0; n < 4; ++n) {
            int col   = wc * 64 + n * 16 + lrow;
            float sxj = snxB[col];
            float syj = snyB[col];
#pragma unroll
            for (int r = 0; r < 4; ++r) {
                int rowi  = wr * 64 + m * 16 + kgrp * 4 + r;
                float d2x = snxA[rowi] + sxj - 2.f * accX[m][n][r];
                float dxv = sqrtf(fmaxf(d2x, 1e-12f));
                float d2y = snyA[rowi] + syj - 2.f * accY[m][n][r];
                float dyv = sqrtf(fmaxf(d2y, 1e-12f));
                int gi = iA + rowi, gj = iB + col;
                bool keep = (gi != gj) && (dxv <= EPS_THR);
                float contrib = __expf(-dxv * SIGMA_INV) * dyv;
                local += keep ? contrib : 0.f;
            }
        }
    }
    if (!diag) local *= 2.f;

#pragma unroll
    for (int off = 32; off > 0; off >>= 1)
        local += __shfl_down(local, off, 64);
    if (lane == 0) wsum[wid] = local;
    __syncthreads();
    if (tid == 0)
        atomicAdd(out, wsum[0] + wsum[1] + wsum[2] + wsum[3]);
}

// ===========================================================================
// FALLBACK PATH (bf16, round-2 structure) — used only if ws too small.
// ===========================================================================
__global__ void norms_kernel_fb(const float* __restrict__ x,
                                const float* __restrict__ y,
                                float* __restrict__ sqx,
                                float* __restrict__ sqy) {
    int row = blockIdx.x;
    int t   = threadIdx.x;
    const float4* xr = (const float4*)(x + (size_t)row * D_X);
    float sx = 0.f;
#pragma unroll
    for (int i = 0; i < D_X / 4 / 64; ++i) {
        float4 v = xr[t + i * 64];
        sx += v.x * v.x + v.y * v.y + v.z * v.z + v.w * v.w;
    }
    const float4* yr = (const float4*)(y + (size_t)row * D_Y);
    float sy = 0.f;
#pragma unroll
    for (int i = 0; i < D_Y / 4 / 64; ++i) {
        float4 v = yr[t + i * 64];
        sy += v.x * v.x + v.y * v.y + v.z * v.z + v.w * v.w;
    }
#pragma unroll
    for (int off = 32; off > 0; off >>= 1) {
        sx += __shfl_down(sx, off, 64);
        sy += __shfl_down(sy, off, 64);
    }
    if (t == 0) { sqx[row] = sx; sqy[row] = sy; }
}

__device__ __forceinline__ void stage_tile_fb(const float* __restrict__ src, int ld,
                                              int base_row, int k0,
                                              u16x8* __restrict__ dst, int tid) {
#pragma unroll
    for (int it = 0; it < 2; ++it) {
        int u   = tid + it * 256;
        int row = u >> 2;
        int q   = u & 3;
        const float4* p = (const float4*)(src + (size_t)(base_row + row) * ld + k0 + q * 16);
        float4 f0 = p[0], f1 = p[1], f2 = p[2], f3 = p[3];
        u16x8 lo, hi;
        lo[0] = f32_to_bf16_bits(f0.x); lo[1] = f32_to_bf16_bits(f0.y);
        lo[2] = f32_to_bf16_bits(f0.z); lo[3] = f32_to_bf16_bits(f0.w);
        lo[4] = f32_to_bf16_bits(f1.x); lo[5] = f32_to_bf16_bits(f1.y);
        lo[6] = f32_to_bf16_bits(f1.z); lo[7] = f32_to_bf16_bits(f1.w);
        hi[0] = f32_to_bf16_bits(f2.x); hi[1] = f32_to_bf16_bits(f2.y);
        hi[2] = f32_to_bf16_bits(f2.z); hi[3] = f32_to_bf16_bits(f2.w);
        hi[4] = f32_to_bf16_bits(f3.x); hi[5] = f32_to_bf16_bits(f3.y);
        hi[6] = f32_to_bf16_bits(f3.z); hi[7] = f32_to_bf16_bits(f3.w);
        int swz = row & 7;
        dst[row * 8 + ((2 * q) ^ swz)]     = lo;
        dst[row * 8 + ((2 * q + 1) ^ swz)] = hi;
    }
}

__device__ __forceinline__ void mfma16_fb(const bf16x8 a[4], const bf16x8 b[4],
                                          f32x4 acc[4][4]) {
#pragma unroll
    for (int m = 0; m < 4; ++m)
#pragma unroll
        for (int n = 0; n < 4; ++n)
            acc[m][n] = __builtin_amdgcn_mfma_f32_16x16x32_bf16(
                a[m], b[n], acc[m][n], 0, 0, 0);
}

__device__ __forceinline__ void load_frags_fb(const u16x8* As_, const u16x8* Bs_,
                                              int wr, int wc, int lrow, int kgrp,
                                              bf16x8 a[2][4], bf16x8 b[2][4]) {
#pragma unroll
    for (int ks = 0; ks < 2; ++ks) {
#pragma unroll
        for (int m = 0; m < 4; ++m) {
            int row  = wr * 64 + m * 16 + lrow;
            int slot = (ks * 4 + kgrp) ^ (row & 7);
            a[ks][m] = __builtin_bit_cast(bf16x8, As_[row * 8 + slot]);
        }
#pragma unroll
        for (int n = 0; n < 4; ++n) {
            int row  = wc * 64 + n * 16 + lrow;
            int slot = (ks * 4 + kgrp) ^ (row & 7);
            b[ks][n] = __builtin_bit_cast(bf16x8, Bs_[row * 8 + slot]);
        }
    }
}

__global__ void __launch_bounds__(256, 2)
graph_loss_fb(const float* __restrict__ x, const float* __restrict__ y,
              const float* __restrict__ sqx, const float* __restrict__ sqy,
              float* __restrict__ out) {
    __shared__ u16x8 As[BM * 8];
    __shared__ u16x8 Bs[BM * 8];
    __shared__ float snxA[BM], snxB[BM], snyA[BM], snyB[BM];
    __shared__ float wsum[4];

    const int tid  = threadIdx.x;
    const int lane = tid & 63;
    const int wid  = tid >> 6;
    const int wr   = wid >> 1;
    const int wc   = wid & 1;
    const int lrow = lane & 15;
    const int kgrp = lane >> 4;

    int t = blockIdx.x, bi = 0;
    while (t >= NT - bi) { t -= NT - bi; ++bi; }
    const int bj = bi + t;
    const int iA = bi * BM;
    const int iB = bj * BM;

    if (tid < BM) {
        snxA[tid] = sqx[iA + tid];
        snyA[tid] = sqy[iA + tid];
        snxB[tid] = sqx[iB + tid];
        snyB[tid] = sqy[iB + tid];
    }

    f32x4 accX[4][4] = {};
    f32x4 accY[4][4] = {};
    bf16x8 a[2][4], b[2][4];

    for (int kt = 0; kt < D_X / 64; ++kt) {
        __syncthreads();
        stage_tile_fb(x, D_X, iA, kt * 64, As, tid);
        stage_tile_fb(x, D_X, iB, kt * 64, Bs, tid);
        __syncthreads();
        load_frags_fb(As, Bs, wr, wc, lrow, kgrp, a, b);
#pragma unroll
        for (int ks = 0; ks < 2; ++ks) mfma16_fb(a[ks], b[ks], accX);
    }
    for (int kt = 0; kt < D_Y / 64; ++kt) {
        __syncthreads();
        stage_tile_fb(y, D_Y, iA, kt * 64, As, tid);
        stage_tile_fb(y, D_Y, iB, kt * 64, Bs, tid);
        __syncthreads();
        load_frags_fb(As, Bs, wr, wc, lrow, kgrp, a, b);
#pragma unroll
        for (int ks = 0; ks < 2; ++ks) mfma16_fb(a[ks], b[ks], accY);
    }

    float local = 0.f;
#pragma unroll
    for (int m = 0; m < 4; ++m) {
#pragma unroll
        for (int n = 0; n < 4; ++n) {
            int col   = wc * 64 + n * 16 + lrow;
            float sxj = snxB[col];
            float syj = snyB[col];
#pragma unroll
            for (int r = 0; r < 4; ++r) {
                int rowi  = wr * 64 + m * 16 + kgrp * 4 + r;
                float d2x = snxA[rowi] + sxj - 2.f * accX[m][n][r];
                float dxv = sqrtf(fmaxf(d2x, 1e-12f));
                float d2y = snyA[rowi] + syj - 2.f * accY[m][n][r];
                float dyv = sqrtf(fmaxf(d2y, 1e-12f));
                int gi = iA + rowi, gj = iB + col;
                bool keep = (gi != gj) && (dxv <= EPS_THR);
                float contrib = __expf(-dxv * SIGMA_INV) * dyv;
                local += keep ? contrib : 0.f;
            }
        }
    }
    if (bi != bj) local *= 2.f;

#pragma unroll
    for (int off = 32; off > 0; off >>= 1)
        local += __shfl_down(local, off, 64);
    if (lane == 0) wsum[wid] = local;
    __syncthreads();
    if (tid == 0)
        atomicAdd(out, wsum[0] + wsum[1] + wsum[2] + wsum[3]);
}

// ===========================================================================
extern "C" void kernel_launch(void* const* d_in, const int* in_sizes, int n_in,
                              void* d_out, int out_size, void* d_ws, size_t ws_size,
                              hipStream_t stream) {
    const float* x = (const float*)d_in[0];
    const float* y = (const float*)d_in[1];
    float* out = (float*)d_out;

    hipMemsetAsync(d_out, 0, sizeof(float) * (size_t)out_size, stream);

    const size_t xq_bytes = (size_t)BATCH * D_X;        // 4 MB fp8
    const size_t yq_bytes = (size_t)BATCH * D_Y;        // 2 MB fp8
    const size_t sq_bytes = 2 * (size_t)BATCH * sizeof(float);
    const size_t need = xq_bytes + yq_bytes + sq_bytes;

    if (ws_size >= need) {
        u64*   xq  = (u64*)d_ws;
        u64*   yq  = (u64*)((char*)d_ws + xq_bytes);
        float* sqx = (float*)((char*)d_ws + xq_bytes + yq_bytes);
        float* sqy = sqx + BATCH;
        convert_fp8<<<BATCH, 192, 0, stream>>>(x, y, xq, yq, sqx, sqy);
        gram_fp8<<<NBLKF, 256, 0, stream>>>((const u16x8*)xq, (const u16x8*)yq,
                                            sqx, sqy, out);
    } else {
        float* sqx = (float*)d_ws;
        float* sqy = sqx + BATCH;
        norms_kernel_fb<<<BATCH, 64, 0, stream>>>(x, y, sqx, sqy);
        graph_loss_fb<<<NBLK, 256, 0, stream>>>(x, y, sqx, sqy, out);
    }
}